// Round 5
// baseline (301.444 us; speedup 1.0000x reference)
//
#include <hip/hip_runtime.h>
#include <math.h>

// (B, T, D, H, L) = (8, 512, 128, 128, 2). All fp32 I/O.
#define BB 8
#define TT 512
#define DD 128
#define HH 128
#define BT_ (BB * TT)                 // 4096
static const size_t BTH = (size_t)BT_ * HH;  // 524288

// ws layout: act planes [0,6*BTH) : q | k | ifpack(2*BTH) | vopack(2*BTH)
//   q:      act + 0      [row][h]
//   k:      act + BTH    [row][h]     (pre-scaled by 1/sqrt(H) in proj)
//   ifpack: act + 2*BTH  [row][2h+{0:i,1:f}]
//   vopack: act + 4*BTH  [row][2h+{0:v,1:o}]  (o *= invden in nexp_denom)
// hbuf = act + 6*BTH (layer-1 output, planar [row][h]).
// cbuf = act + 7*BTH: chunked C-scan summaries / chunk-start C's
//   (1024 chains x 8 chunks x 128 cols = 4 MB), abuf after it (8192 floats).
//   Only used if ws_size is large enough; else fallback single-pass scan.
// d_out scratch map (floats):
//   [0,        196608)  Wt   (12 x 128 x 128 transposed weights)
//   [196608,   327680)  segAB[b][p][seg]{A,B}   (8*128*64*2)
//   [327680,   393216)  nstart[b][p][seg]       (8*128*64)
// All consumed before the final hscan overwrites d_out (stream-ordered).

struct WArgs { const float* W[6]; };
struct BArgs { const float* b[6]; };

template <int CTRL>
__device__ __forceinline__ float dpp_add(float x) {
  int y = __builtin_amdgcn_update_dpp(0, __builtin_bit_cast(int, x), CTRL,
                                      0xF, 0xF, true);
  return x + __builtin_bit_cast(float, y);
}

// DPP move with identity fill: invalid lanes keep `old` (bound_ctrl=false).
template <int CTRL>
__device__ __forceinline__ float dpp_mov(float old, float x) {
  int y = __builtin_amdgcn_update_dpp(__builtin_bit_cast(int, old),
                                      __builtin_bit_cast(int, x), CTRL,
                                      0xF, 0xF, false);
  return __builtin_bit_cast(float, y);
}

__device__ __forceinline__ float rd_lane(float x, int l) {
  return __builtin_bit_cast(
      float, __builtin_amdgcn_readlane(__builtin_bit_cast(int, x), l));
}

// ---------------------------------------------------------------------------
// Transpose all 12 weight slabs: Wt[l*6+p][d][h] = W_p[l][h][d].
// ---------------------------------------------------------------------------
__global__ __launch_bounds__(256)
void transpose_w(WArgs w, float* __restrict__ Wt) {
  __shared__ float t[32][33];
  const int l = blockIdx.y / 6, p = blockIdx.y % 6;
  const float* src = w.W[p] + (size_t)l * HH * DD;
  float* dst = Wt + (size_t)blockIdx.y * HH * DD;
  const int ty0 = (blockIdx.x >> 2) * 32, tx0 = (blockIdx.x & 3) * 32;
  const int tx = threadIdx.x & 31, ty = threadIdx.x >> 5;
#pragma unroll
  for (int j = 0; j < 32; j += 8)
    t[ty + j][tx] = src[(size_t)(ty0 + ty + j) * DD + tx0 + tx];
  __syncthreads();
#pragma unroll
  for (int j = 0; j < 32; j += 8)
    dst[(size_t)(tx0 + ty + j) * HH + ty0 + tx] = t[tx][ty + j];
}

// ---------------------------------------------------------------------------
// Projection: out[p][row][h] = act_p( sum_d X[row][d] * Wt_p[d][h] + b_p[h] )
// grid (BT_/32, 6), block 256. Thread = 2 rows x 8 h.
// ---------------------------------------------------------------------------
__global__ __launch_bounds__(256)
void proj_kernel(const float* __restrict__ X, const float* __restrict__ Wtl,
                 BArgs args, float* __restrict__ act) {
  __shared__ float xs[32][132];
  const int p = blockIdx.y;
  const int row0 = blockIdx.x * 32;
  const int tid = threadIdx.x;
  {
    const float4* xg = (const float4*)(X + (size_t)row0 * DD);
#pragma unroll
    for (int i = 0; i < 4; ++i) {
      int u = tid + 256 * i;
      float4 v = xg[u];
      *(float4*)&xs[u >> 5][(u & 31) * 4] = v;
    }
  }
  __syncthreads();

  const int h0 = (tid & 15) * 8;
  const int r0 = (tid >> 4) * 2;
  const float* wtp = Wtl + (size_t)p * HH * DD;

  float acc[2][8];
#pragma unroll
  for (int r = 0; r < 2; ++r)
#pragma unroll
    for (int j = 0; j < 8; ++j) acc[r][j] = 0.f;

  for (int d0 = 0; d0 < DD; d0 += 4) {
    float4 wa[4], wb[4];
#pragma unroll
    for (int i = 0; i < 4; ++i) {
      wa[i] = *(const float4*)(wtp + (size_t)(d0 + i) * HH + h0);
      wb[i] = *(const float4*)(wtp + (size_t)(d0 + i) * HH + h0 + 4);
    }
    float4 x0 = *(const float4*)&xs[r0][d0];
    float4 x1 = *(const float4*)&xs[r0 + 1][d0];
    const float xa[4] = {x0.x, x0.y, x0.z, x0.w};
    const float xb[4] = {x1.x, x1.y, x1.z, x1.w};
#pragma unroll
    for (int i = 0; i < 4; ++i) {
      acc[0][0] = fmaf(xa[i], wa[i].x, acc[0][0]);
      acc[0][1] = fmaf(xa[i], wa[i].y, acc[0][1]);
      acc[0][2] = fmaf(xa[i], wa[i].z, acc[0][2]);
      acc[0][3] = fmaf(xa[i], wa[i].w, acc[0][3]);
      acc[0][4] = fmaf(xa[i], wb[i].x, acc[0][4]);
      acc[0][5] = fmaf(xa[i], wb[i].y, acc[0][5]);
      acc[0][6] = fmaf(xa[i], wb[i].z, acc[0][6]);
      acc[0][7] = fmaf(xa[i], wb[i].w, acc[0][7]);
      acc[1][0] = fmaf(xb[i], wa[i].x, acc[1][0]);
      acc[1][1] = fmaf(xb[i], wa[i].y, acc[1][1]);
      acc[1][2] = fmaf(xb[i], wa[i].z, acc[1][2]);
      acc[1][3] = fmaf(xb[i], wa[i].w, acc[1][3]);
      acc[1][4] = fmaf(xb[i], wb[i].x, acc[1][4]);
      acc[1][5] = fmaf(xb[i], wb[i].y, acc[1][5]);
      acc[1][6] = fmaf(xb[i], wb[i].z, acc[1][6]);
      acc[1][7] = fmaf(xb[i], wb[i].w, acc[1][7]);
    }
  }

  const float4 b0 = *(const float4*)(args.b[p] + h0);
  const float4 b1 = *(const float4*)(args.b[p] + h0 + 4);
  const float bias[8] = {b0.x, b0.y, b0.z, b0.w, b1.x, b1.y, b1.z, b1.w};
#pragma unroll
  for (int r = 0; r < 2; ++r) {
    const size_t row = (size_t)row0 + r0 + r;
    float v[8];
#pragma unroll
    for (int j = 0; j < 8; ++j) {
      float a = acc[r][j] + bias[j];
      if (p == 1)      a *= 0.088388347648318447f;   // 1/sqrt(128)
      else if (p == 3) a = __expf(a);
      else if (p >= 4) a = 1.0f / (1.0f + __expf(-a));
      v[j] = a;
    }
    if (p == 0) {
      float* dst = act + row * HH + h0;
      *(float4*)dst = make_float4(v[0], v[1], v[2], v[3]);
      *(float4*)(dst + 4) = make_float4(v[4], v[5], v[6], v[7]);
    } else if (p == 1) {
      float* dst = act + BTH + row * HH + h0;
      *(float4*)dst = make_float4(v[0], v[1], v[2], v[3]);
      *(float4*)(dst + 4) = make_float4(v[4], v[5], v[6], v[7]);
    } else if (p == 3 || p == 4) {       // i -> slot 0, f -> slot 1
      float* dst = act + 2 * BTH + row * 2 * HH + 2 * h0 + (p == 3 ? 0 : 1);
#pragma unroll
      for (int j = 0; j < 8; ++j) dst[2 * j] = v[j];
    } else {                             // v -> slot 0, o -> slot 1
      float* dst = act + 4 * BTH + row * 2 * HH + 2 * h0 + (p == 2 ? 0 : 1);
#pragma unroll
      for (int j = 0; j < 8; ++j) dst[2 * j] = v[j];
    }
  }
}

// ---------------------------------------------------------------------------
// n-recurrence (independent of C), parallel scan over T.
// ---------------------------------------------------------------------------
__global__ __launch_bounds__(128)
void nseg_kernel(const float* __restrict__ act, float* __restrict__ segAB) {
  const int b = blockIdx.x & 7, seg = blockIdx.x >> 3;
  const int p = threadIdx.x;
  const size_t boff = (size_t)b * TT * HH;
  const float* kp = act + BTH + boff + p;
  const float* ifp = act + 2 * BTH + 2 * boff + 2 * p;
  const int t0 = seg * 8;
  float A = 1.f, Bv = 0.f;
#pragma unroll
  for (int j = 0; j < 8; ++j) {
    const float2 iff = *(const float2*)(ifp + (size_t)(t0 + j) * 2 * HH);
    const float kv = kp[(size_t)(t0 + j) * HH];
    A *= iff.y;
    Bv = fmaf(iff.y, Bv, iff.x * kv);
  }
  *(float2*)(segAB + ((size_t)(b * 128 + p) * 64 + seg) * 2) =
      make_float2(A, Bv);
}

__global__ __launch_bounds__(64)
void nsum_kernel(const float* __restrict__ segAB, float* __restrict__ nstart) {
  const int chain = blockIdx.x;       // b*128+p
  const int lane = threadIdx.x;
  const float2 ab = *(const float2*)(segAB + ((size_t)chain * 64 + lane) * 2);
  float A = ab.x, Bv = ab.y;
#define SCAN_LVL(CTRL)                          \
  {                                             \
    float As = dpp_mov<CTRL>(1.0f, A);          \
    float Bs = dpp_mov<CTRL>(0.0f, Bv);         \
    Bv = fmaf(A, Bs, Bv);                       \
    A = A * As;                                 \
  }
  SCAN_LVL(0x111)
  SCAN_LVL(0x112)
  SCAN_LVL(0x114)
  SCAN_LVL(0x118)
  SCAN_LVL(0x142)
  SCAN_LVL(0x143)
#undef SCAN_LVL
  const int idx = (lane + 1) & 63;
  nstart[(size_t)chain * 64 + idx] = (lane == 63) ? 0.f : Bv;
}

// Phase 3 + denom fused: re-run 8 local n-steps from segment-start n,
// block-reduce dot(n_{t-1}, q_t), scale the o-slot in place by 1/max(|d|,1).
__global__ __launch_bounds__(128)
void nexp_denom_kernel(float* __restrict__ act,
                       const float* __restrict__ nstart) {
  __shared__ float pl[8][132];
  __shared__ float den[8];
  const int b = blockIdx.x & 7, seg = blockIdx.x >> 3;
  const int p = threadIdx.x;
  const size_t boff = (size_t)b * TT * HH;
  const float* qp = act + boff + p;
  const float* kp = act + BTH + boff + p;
  const float* ifp = act + 2 * BTH + 2 * boff + 2 * p;
  const int t0 = seg * 8;
  float n = nstart[(size_t)(b * 128 + p) * 64 + seg];
  float prod[8];
#pragma unroll
  for (int j = 0; j < 8; ++j) {
    const float2 iff = *(const float2*)(ifp + (size_t)(t0 + j) * 2 * HH);
    const float kv = kp[(size_t)(t0 + j) * HH];
    const float qv = qp[(size_t)(t0 + j) * HH];
    prod[j] = n * qv;                  // n_{t-1}[p] * q_t[p]
    n = fmaf(iff.y, n, iff.x * kv);
  }
#pragma unroll
  for (int j = 0; j < 8; ++j) pl[j][p] = prod[j];
  __syncthreads();
  {
    const int j = p >> 4, c = p & 15;  // 16 threads per t
    const float4 a = *(const float4*)&pl[j][c * 8];
    const float4 d = *(const float4*)&pl[j][c * 8 + 4];
    float s = ((a.x + a.y) + (a.z + a.w)) + ((d.x + d.y) + (d.z + d.w));
    s = dpp_add<0x111>(s);
    s = dpp_add<0x112>(s);
    s = dpp_add<0x114>(s);
    s = dpp_add<0x118>(s);             // lane 15 of each 16-row = full sum
    if ((p & 15) == 15)
      den[j] = __builtin_amdgcn_rcpf(fmaxf(fabsf(s), 1.0f));
  }
  __syncthreads();
  float* vop = act + 4 * BTH + 2 * boff;
#pragma unroll
  for (int j = 0; j < 8; ++j)
    vop[(size_t)(t0 + j) * 2 * HH + 2 * p + 1] *= den[j];
}

// ---------------------------------------------------------------------------
// Chunked C-scan. C_t[p][c] = f_t[p]*C_{t-1}[p][c] + (i_t[p]*v_t[p])*k_t[c]
// is an affine scan per element with a per-(b,p,t) scalar coefficient.
// T is split into 8 chunks of 64. cseg computes per-chunk summaries
// (A = prod f scalar, B[c] 128-vector); ccomb composes them in place into
// chunk-START C's; hscan replays each chunk from its exact start C with the
// full h pipeline. 8192 independent waves (vs 1024) -> ~4 waves/SIMD.
// ---------------------------------------------------------------------------
struct SG {
  float2 k[8];
  float2 gf, gv;     // (i,f) and (v,o') at t = t0 + (lane>>3)
};

__global__ __launch_bounds__(64)
void cseg_kernel(const float* __restrict__ act, float* __restrict__ cbuf,
                 float* __restrict__ abuf) {
  const int lane = threadIdx.x;
  const int blk = blockIdx.x;
  const int b = blk & 7, p = (blk >> 3) & 127, g = blk >> 10;
  const int tbase = g * 64;
  const size_t boff = (size_t)b * TT * HH;
  const float* kp = act + BTH + boff + 2 * lane;
  const float* ifp = act + 2 * BTH + 2 * boff + 2 * p;
  const float* vop = act + 4 * BTH + 2 * boff + 2 * p;
  const int tsub = lane >> 3;

  float B0 = 0.f, B1 = 0.f, Af = 1.f;
  SG A, B;

  auto load = [&](int gl, SG& s) {
    const int t0 = tbase + 8 * gl;
#pragma unroll
    for (int j = 0; j < 8; ++j)
      s.k[j] = *(const float2*)(kp + (size_t)(t0 + j) * HH);
    const size_t go = (size_t)(t0 + tsub) * 2 * HH;
    s.gf = *(const float2*)(ifp + go);
    s.gv = *(const float2*)(vop + go);
  };
  auto step8 = [&](const SG& s) {
    const float ar = s.gf.x * s.gv.x;
#pragma unroll
    for (int j = 0; j < 8; ++j) {
      const float sf = rd_lane(s.gf.y, 8 * j);
      const float sa = rd_lane(ar, 8 * j);
      B0 = fmaf(sf, B0, sa * s.k[j].x);
      B1 = fmaf(sf, B1, sa * s.k[j].y);
      Af *= sf;
    }
  };

  load(0, A);
  load(1, B);
#pragma unroll 1
  for (int gl = 0; gl < 8; gl += 2) {
    step8(A);
    if (gl + 2 < 8) load(gl + 2, A);
    step8(B);
    if (gl + 3 < 8) load(gl + 3, B);
  }
  const size_t slot = (size_t)(b * 128 + p) * 8 + g;
  *(float2*)(cbuf + slot * 128 + 2 * lane) = make_float2(B0, B1);
  if (lane == 0) abuf[slot] = Af;
}

// Compose the 8 chunk summaries per chain, in place: slot g gets the C at the
// START of chunk g (slot 0 = zeros). Cs_{g+1} = A_g * Cs_g + B_g.
__global__ __launch_bounds__(64)
void ccomb_kernel(float* __restrict__ cbuf, const float* __restrict__ abuf) {
  const int chain = blockIdx.x;        // b*128+p
  const int lane = threadIdx.x;
  const float av = abuf[(size_t)chain * 8 + (lane & 7)];
  float Cs0 = 0.f, Cs1 = 0.f;
#pragma unroll
  for (int g = 0; g < 8; ++g) {
    float* ptr = cbuf + ((size_t)chain * 8 + g) * 128 + 2 * lane;
    const float2 Bv = *(const float2*)ptr;
    const float Ag = rd_lane(av, g);
    *(float2*)ptr = make_float2(Cs0, Cs1);
    Cs0 = fmaf(Ag, Cs0, Bv.x);
    Cs1 = fmaf(Ag, Cs1, Bv.y);
  }
}

// ---------------------------------------------------------------------------
// hscan: replay a chunk of NG 8-step groups from its start C, full h output.
// Identical machinery to the proven v2 scan (barrier-free, 1 wave/block,
// 2 cols/lane, LDS-transpose h-reduce pipelined one group behind).
// grid 1024*G: b = blk&7, p = (blk>>3)&127, g = blk>>10, tbase = g*8*NG.
// cbuf == nullptr -> C starts at zero (single-chunk fallback, NG=64).
// ---------------------------------------------------------------------------
struct HG {
  float2 q[8], k[8];
  float2 gf, gv;     // (i,f) and (v,o') at t = t0 + (lane>>3)
};

__global__ __launch_bounds__(64)
void hscan_kernel(const float* __restrict__ act, float* __restrict__ hout,
                  const float* __restrict__ cbuf, int NG) {
  __shared__ __align__(16) float red[2][8][68];
  const int lane = threadIdx.x;
  const int blk = blockIdx.x;
  const int b = blk & 7;
  const int p = (blk >> 3) & 127;
  const int g = blk >> 10;
  const int tbase = g * 8 * NG;
  const size_t boff = (size_t)b * TT * HH;
  const float* qp = act + boff + 2 * lane;
  const float* kp = act + BTH + boff + 2 * lane;
  const float* ifp = act + 2 * BTH + 2 * boff + 2 * p;
  const float* vop = act + 4 * BTH + 2 * boff + 2 * p;
  const int tsub = lane >> 3;
  const int rj = lane >> 3, rr = lane & 7;
  float* hbase = hout + (size_t)b * TT * HH + p;

  float C0 = 0.f, C1 = 0.f;
  if (cbuf) {
    const float2 cs = *(const float2*)(
        cbuf + ((size_t)(b * 128 + p) * 8 + g) * 128 + 2 * lane);
    C0 = cs.x;
    C1 = cs.y;
  }

  auto load_group = [&](int gl, HG& s) {
    const int t0 = tbase + 8 * gl;
#pragma unroll
    for (int j = 0; j < 8; ++j) {
      s.q[j] = *(const float2*)(qp + (size_t)(t0 + j) * HH);
      s.k[j] = *(const float2*)(kp + (size_t)(t0 + j) * HH);
    }
    const size_t go = (size_t)(t0 + tsub) * 2 * HH;
    s.gf = *(const float2*)(ifp + go);
    s.gv = *(const float2*)(vop + go);
  };

  auto compute_steps = [&](const HG& s, int par) {
    const float ar = s.gf.x * s.gv.x;    // i*v at t0+tsub
    float pj[8];
#pragma unroll
    for (int j = 0; j < 8; ++j) {
      const float sf = rd_lane(s.gf.y, 8 * j);
      const float sa = rd_lane(ar, 8 * j);
      pj[j] = fmaf(C0, s.q[j].x, C1 * s.q[j].y);   // OLD C
      C0 = fmaf(sf, C0, sa * s.k[j].x);
      C1 = fmaf(sf, C1, sa * s.k[j].y);
    }
#pragma unroll
    for (int j = 0; j < 8; ++j) red[par][j][lane] = pj[j];
  };

  auto reduce_group = [&](int par, int gl, float oh) {
    const float4 a = *(const float4*)&red[par][rj][rr * 8];
    const float4 c = *(const float4*)&red[par][rj][rr * 8 + 4];
    float s = ((a.x + a.y) + (a.z + a.w)) + ((c.x + c.y) + (c.z + c.w));
    s = dpp_add<0x111>(s);
    s = dpp_add<0x112>(s);
    s = dpp_add<0x114>(s);               // lane 8*rj+7 = full sum for t0+rj
    if (rr == 7) hbase[(size_t)(tbase + 8 * gl + rj) * HH] = s * oh;
  };

  HG A, B;
  load_group(0, A);
  load_group(1, B);
  compute_steps(A, 0);
  float om = A.gv.y;                     // oh of group 0 (pending reduce)
  load_group(2 < NG - 1 ? 2 : NG - 1, A);

  const int half = (NG - 2) >> 1;
#pragma unroll 1
  for (int gg = 0; gg < half; ++gg) {
    const int g1 = 2 * gg + 1;
    compute_steps(B, 1);
    const float o1 = B.gv.y;
    load_group(g1 + 2 < NG ? g1 + 2 : NG - 1, B);
    reduce_group(0, g1 - 1, om);
    om = o1;
    const int g2 = g1 + 1;
    compute_steps(A, 0);
    const float o2 = A.gv.y;
    load_group(g2 + 2 < NG ? g2 + 2 : NG - 1, A);
    reduce_group(1, g2 - 1, om);
    om = o2;
  }
  // computed 0..NG-2, reduced 0..NG-3; B holds group NG-1
  compute_steps(B, 1);
  reduce_group(0, NG - 2, om);
  reduce_group(1, NG - 1, B.gv.y);
}

// ---------------------------------------------------------------------------
extern "C" void kernel_launch(void* const* d_in, const int* in_sizes, int n_in,
                              void* d_out, int out_size, void* d_ws,
                              size_t ws_size, hipStream_t stream) {
  (void)in_sizes; (void)n_in; (void)out_size;
  const float* x = (const float*)d_in[0];
  float* act = (float*)d_ws;            // 6 * BTH floats
  float* hbuf = act + 6 * BTH;          // BTH floats (layer-1 h)
  float* cbuf = act + 7 * BTH;          // 1024*8*128 floats (if ws allows)
  float* abuf = cbuf + (size_t)1024 * 8 * 128;  // 8192 floats
  float* Wt = (float*)d_out;            // [0, 196608)
  float* segAB = Wt + 196608;           // [196608, 327680)
  float* nstart = Wt + 327680;          // [327680, 393216)

  const size_t need =
      ((size_t)7 * BTH + (size_t)1024 * 8 * 128 + 8192) * sizeof(float);
  const bool fast = ws_size >= need;

  WArgs wa;
  for (int j = 0; j < 6; ++j) wa.W[j] = (const float*)d_in[1 + j];
  transpose_w<<<dim3(16, 12), 256, 0, stream>>>(wa, Wt);

  for (int l = 0; l < 2; ++l) {
    BArgs ba;
    for (int j = 0; j < 6; ++j)
      ba.b[j] = (const float*)d_in[7 + j] + (size_t)l * HH;
    const float* wtl = Wt + (size_t)l * 6 * HH * DD;
    const float* xin = (l == 0) ? x : hbuf;
    float* hdst = (l == 0) ? hbuf : (float*)d_out;
    proj_kernel<<<dim3(BT_ / 32, 6), 256, 0, stream>>>(xin, wtl, ba, act);
    // n/denominator path (independent of C)
    nseg_kernel<<<512, 128, 0, stream>>>(act, segAB);
    nsum_kernel<<<1024, 64, 0, stream>>>(segAB, nstart);
    nexp_denom_kernel<<<512, 128, 0, stream>>>(act, nstart);
    if (fast) {
      // chunked C-scan: 8 chunks of 64 -> 8192 independent waves
      cseg_kernel<<<8192, 64, 0, stream>>>(act, cbuf, abuf);
      ccomb_kernel<<<1024, 64, 0, stream>>>(cbuf, abuf);
      hscan_kernel<<<8192, 64, 0, stream>>>(act, hdst, cbuf, 8);
    } else {
      hscan_kernel<<<1024, 64, 0, stream>>>(act, hdst, nullptr, 64);
    }
  }
}

// Round 6
// 220.492 us; speedup vs baseline: 1.3671x; 1.3671x over previous
//
#include <hip/hip_runtime.h>
#include <math.h>

// (B, T, D, H, L) = (8, 512, 128, 128, 2). All fp32 I/O.
#define BB 8
#define TT 512
#define DD 128
#define HH 128
#define BT_ (BB * TT)                 // 4096
#define CL 64                         // C-scan chunk length
#define NCH 8                         // number of chunks (TT/CL)
static const size_t BTH = (size_t)BT_ * HH;  // 524288

// ws layout: act planes [0,6*BTH) : q | k | ifpack(2*BTH) | vopack(2*BTH)
//   q:      act + 0      [row][h]
//   k:      act + BTH    [row][h]     (pre-scaled by 1/sqrt(H) in proj)
//   ifpack: act + 2*BTH  [row][2h+{0:i,1:f}]
//   vopack: act + 4*BTH  [row][2h+{0:v,1:o}]  (o *= invden in nexp_denom)
// hbuf = act + 6*BTH (layer-1 output). cbuf = act + 7*BTH (4 MB chunk
// summaries / start-C), abuf after it (8192 floats). Fallback if ws small.
// d_out scratch: Wt [0,196608) | segAB [196608,327680) | nstart [327680,393216)
// all consumed before the final hscan overwrites d_out (stream-ordered).

struct WArgs { const float* W[6]; };
struct BArgs { const float* b[6]; };

template <int CTRL>
__device__ __forceinline__ float dpp_add(float x) {
  int y = __builtin_amdgcn_update_dpp(0, __builtin_bit_cast(int, x), CTRL,
                                      0xF, 0xF, true);
  return x + __builtin_bit_cast(float, y);
}

template <int CTRL>
__device__ __forceinline__ float dpp_mov(float old, float x) {
  int y = __builtin_amdgcn_update_dpp(__builtin_bit_cast(int, old),
                                      __builtin_bit_cast(int, x), CTRL,
                                      0xF, 0xF, false);
  return __builtin_bit_cast(float, y);
}

__device__ __forceinline__ float rd_lane(float x, int l) {
  return __builtin_bit_cast(
      float, __builtin_amdgcn_readlane(__builtin_bit_cast(int, x), l));
}

// ---------------------------------------------------------------------------
// Transpose all 12 weight slabs: Wt[l*6+p][d][h] = W_p[l][h][d].
// ---------------------------------------------------------------------------
__global__ __launch_bounds__(256)
void transpose_w(WArgs w, float* __restrict__ Wt) {
  __shared__ float t[32][33];
  const int l = blockIdx.y / 6, p = blockIdx.y % 6;
  const float* src = w.W[p] + (size_t)l * HH * DD;
  float* dst = Wt + (size_t)blockIdx.y * HH * DD;
  const int ty0 = (blockIdx.x >> 2) * 32, tx0 = (blockIdx.x & 3) * 32;
  const int tx = threadIdx.x & 31, ty = threadIdx.x >> 5;
#pragma unroll
  for (int j = 0; j < 32; j += 8)
    t[ty + j][tx] = src[(size_t)(ty0 + ty + j) * DD + tx0 + tx];
  __syncthreads();
#pragma unroll
  for (int j = 0; j < 32; j += 8)
    dst[(size_t)(tx0 + ty + j) * HH + ty0 + tx] = t[tx][ty + j];
}

// ---------------------------------------------------------------------------
// Projection: out[p][row][h] = act_p( sum_d X[row][d] * Wt_p[d][h] + b_p[h] )
// grid (BT_/32, 6), block 256. Thread = 2 rows x 8 h.
// ---------------------------------------------------------------------------
__global__ __launch_bounds__(256)
void proj_kernel(const float* __restrict__ X, const float* __restrict__ Wtl,
                 BArgs args, float* __restrict__ act) {
  __shared__ float xs[32][132];
  const int p = blockIdx.y;
  const int row0 = blockIdx.x * 32;
  const int tid = threadIdx.x;
  {
    const float4* xg = (const float4*)(X + (size_t)row0 * DD);
#pragma unroll
    for (int i = 0; i < 4; ++i) {
      int u = tid + 256 * i;
      float4 v = xg[u];
      *(float4*)&xs[u >> 5][(u & 31) * 4] = v;
    }
  }
  __syncthreads();

  const int h0 = (tid & 15) * 8;
  const int r0 = (tid >> 4) * 2;
  const float* wtp = Wtl + (size_t)p * HH * DD;

  float acc[2][8];
#pragma unroll
  for (int r = 0; r < 2; ++r)
#pragma unroll
    for (int j = 0; j < 8; ++j) acc[r][j] = 0.f;

  for (int d0 = 0; d0 < DD; d0 += 4) {
    float4 wa[4], wb[4];
#pragma unroll
    for (int i = 0; i < 4; ++i) {
      wa[i] = *(const float4*)(wtp + (size_t)(d0 + i) * HH + h0);
      wb[i] = *(const float4*)(wtp + (size_t)(d0 + i) * HH + h0 + 4);
    }
    float4 x0 = *(const float4*)&xs[r0][d0];
    float4 x1 = *(const float4*)&xs[r0 + 1][d0];
    const float xa[4] = {x0.x, x0.y, x0.z, x0.w};
    const float xb[4] = {x1.x, x1.y, x1.z, x1.w};
#pragma unroll
    for (int i = 0; i < 4; ++i) {
      acc[0][0] = fmaf(xa[i], wa[i].x, acc[0][0]);
      acc[0][1] = fmaf(xa[i], wa[i].y, acc[0][1]);
      acc[0][2] = fmaf(xa[i], wa[i].z, acc[0][2]);
      acc[0][3] = fmaf(xa[i], wa[i].w, acc[0][3]);
      acc[0][4] = fmaf(xa[i], wb[i].x, acc[0][4]);
      acc[0][5] = fmaf(xa[i], wb[i].y, acc[0][5]);
      acc[0][6] = fmaf(xa[i], wb[i].z, acc[0][6]);
      acc[0][7] = fmaf(xa[i], wb[i].w, acc[0][7]);
      acc[1][0] = fmaf(xb[i], wa[i].x, acc[1][0]);
      acc[1][1] = fmaf(xb[i], wa[i].y, acc[1][1]);
      acc[1][2] = fmaf(xb[i], wa[i].z, acc[1][2]);
      acc[1][3] = fmaf(xb[i], wa[i].w, acc[1][3]);
      acc[1][4] = fmaf(xb[i], wb[i].x, acc[1][4]);
      acc[1][5] = fmaf(xb[i], wb[i].y, acc[1][5]);
      acc[1][6] = fmaf(xb[i], wb[i].z, acc[1][6]);
      acc[1][7] = fmaf(xb[i], wb[i].w, acc[1][7]);
    }
  }

  const float4 b0 = *(const float4*)(args.b[p] + h0);
  const float4 b1 = *(const float4*)(args.b[p] + h0 + 4);
  const float bias[8] = {b0.x, b0.y, b0.z, b0.w, b1.x, b1.y, b1.z, b1.w};
#pragma unroll
  for (int r = 0; r < 2; ++r) {
    const size_t row = (size_t)row0 + r0 + r;
    float v[8];
#pragma unroll
    for (int j = 0; j < 8; ++j) {
      float a = acc[r][j] + bias[j];
      if (p == 1)      a *= 0.088388347648318447f;   // 1/sqrt(128)
      else if (p == 3) a = __expf(a);
      else if (p >= 4) a = 1.0f / (1.0f + __expf(-a));
      v[j] = a;
    }
    if (p == 0) {
      float* dst = act + row * HH + h0;
      *(float4*)dst = make_float4(v[0], v[1], v[2], v[3]);
      *(float4*)(dst + 4) = make_float4(v[4], v[5], v[6], v[7]);
    } else if (p == 1) {
      float* dst = act + BTH + row * HH + h0;
      *(float4*)dst = make_float4(v[0], v[1], v[2], v[3]);
      *(float4*)(dst + 4) = make_float4(v[4], v[5], v[6], v[7]);
    } else if (p == 3 || p == 4) {       // i -> slot 0, f -> slot 1
      float* dst = act + 2 * BTH + row * 2 * HH + 2 * h0 + (p == 3 ? 0 : 1);
#pragma unroll
      for (int j = 0; j < 8; ++j) dst[2 * j] = v[j];
    } else {                             // v -> slot 0, o -> slot 1
      float* dst = act + 4 * BTH + row * 2 * HH + 2 * h0 + (p == 2 ? 0 : 1);
#pragma unroll
      for (int j = 0; j < 8; ++j) dst[2 * j] = v[j];
    }
  }
}

// ---------------------------------------------------------------------------
// n-recurrence (independent of C), parallel scan over T. (unchanged, proven)
// ---------------------------------------------------------------------------
__global__ __launch_bounds__(128)
void nseg_kernel(const float* __restrict__ act, float* __restrict__ segAB) {
  const int b = blockIdx.x & 7, seg = blockIdx.x >> 3;
  const int p = threadIdx.x;
  const size_t boff = (size_t)b * TT * HH;
  const float* kp = act + BTH + boff + p;
  const float* ifp = act + 2 * BTH + 2 * boff + 2 * p;
  const int t0 = seg * 8;
  float A = 1.f, Bv = 0.f;
#pragma unroll
  for (int j = 0; j < 8; ++j) {
    const float2 iff = *(const float2*)(ifp + (size_t)(t0 + j) * 2 * HH);
    const float kv = kp[(size_t)(t0 + j) * HH];
    A *= iff.y;
    Bv = fmaf(iff.y, Bv, iff.x * kv);
  }
  *(float2*)(segAB + ((size_t)(b * 128 + p) * 64 + seg) * 2) =
      make_float2(A, Bv);
}

__global__ __launch_bounds__(64)
void nsum_kernel(const float* __restrict__ segAB, float* __restrict__ nstart) {
  const int chain = blockIdx.x;       // b*128+p
  const int lane = threadIdx.x;
  const float2 ab = *(const float2*)(segAB + ((size_t)chain * 64 + lane) * 2);
  float A = ab.x, Bv = ab.y;
#define SCAN_LVL(CTRL)                          \
  {                                             \
    float As = dpp_mov<CTRL>(1.0f, A);          \
    float Bs = dpp_mov<CTRL>(0.0f, Bv);         \
    Bv = fmaf(A, Bs, Bv);                       \
    A = A * As;                                 \
  }
  SCAN_LVL(0x111)
  SCAN_LVL(0x112)
  SCAN_LVL(0x114)
  SCAN_LVL(0x118)
  SCAN_LVL(0x142)
  SCAN_LVL(0x143)
#undef SCAN_LVL
  const int idx = (lane + 1) & 63;
  nstart[(size_t)chain * 64 + idx] = (lane == 63) ? 0.f : Bv;
}

__global__ __launch_bounds__(128)
void nexp_denom_kernel(float* __restrict__ act,
                       const float* __restrict__ nstart) {
  __shared__ float pl[8][132];
  __shared__ float den[8];
  const int b = blockIdx.x & 7, seg = blockIdx.x >> 3;
  const int p = threadIdx.x;
  const size_t boff = (size_t)b * TT * HH;
  const float* qp = act + boff + p;
  const float* kp = act + BTH + boff + p;
  const float* ifp = act + 2 * BTH + 2 * boff + 2 * p;
  const int t0 = seg * 8;
  float n = nstart[(size_t)(b * 128 + p) * 64 + seg];
  float prod[8];
#pragma unroll
  for (int j = 0; j < 8; ++j) {
    const float2 iff = *(const float2*)(ifp + (size_t)(t0 + j) * 2 * HH);
    const float kv = kp[(size_t)(t0 + j) * HH];
    const float qv = qp[(size_t)(t0 + j) * HH];
    prod[j] = n * qv;                  // n_{t-1}[p] * q_t[p]
    n = fmaf(iff.y, n, iff.x * kv);
  }
#pragma unroll
  for (int j = 0; j < 8; ++j) pl[j][p] = prod[j];
  __syncthreads();
  {
    const int j = p >> 4, c = p & 15;  // 16 threads per t
    const float4 a = *(const float4*)&pl[j][c * 8];
    const float4 d = *(const float4*)&pl[j][c * 8 + 4];
    float s = ((a.x + a.y) + (a.z + a.w)) + ((d.x + d.y) + (d.z + d.w));
    s = dpp_add<0x111>(s);
    s = dpp_add<0x112>(s);
    s = dpp_add<0x114>(s);
    s = dpp_add<0x118>(s);             // lane 15 of each 16-row = full sum
    if ((p & 15) == 15)
      den[j] = __builtin_amdgcn_rcpf(fmaxf(fabsf(s), 1.0f));
  }
  __syncthreads();
  float* vop = act + 4 * BTH + 2 * boff;
#pragma unroll
  for (int j = 0; j < 8; ++j)
    vop[(size_t)(t0 + j) * 2 * HH + 2 * p + 1] *= den[j];
}

// ---------------------------------------------------------------------------
// Block-tiled chunked C-scan (v6). One 512-thread block per (b, chunk,
// p-quarter): grid 256 = 1 block/CU, 8 waves = 2/SIMD. Block stages k (and
// q for hscan) tiles + its 32 p's gate slices into LDS ONCE (single barrier,
// no double-buffer) -> q/k read from global exactly once overall. Lane =
// (pl = lane>>4 -> p row, cl = lane&15 -> 8 cols at cl*4+{0..3}+s*64).
// Gates are lane-private (NO readlane broadcast). h-tilde reduce = 4 DPP
// row_shr adds within the hardware 16-lane row; lane cl==15 stores.
// cbuf/abuf layout identical to the proven NCH=8 scheme; ccomb unchanged.
// ---------------------------------------------------------------------------
__global__ __launch_bounds__(512)
void cseg2_kernel(const float* __restrict__ act, float* __restrict__ cbuf,
                  float* __restrict__ abuf) {
  __shared__ __align__(16) float kt[CL][128];   // 32 KB
  __shared__ __align__(16) float ift[CL][64];   // 16 KB (i,f for 32 p's)
  __shared__ __align__(16) float vot[CL][64];   // 16 KB (v,o for 32 p's)
  const int tid = threadIdx.x;
  const int lane = tid & 63, wid = tid >> 6;
  const int blk = blockIdx.x;
  const int b = blk & 7, ch = (blk >> 3) & 7, qtr = blk >> 6;
  const int t0 = ch * CL;
  const int p0 = qtr * 32;
  const size_t boff = (size_t)b * TT * HH;
  const float* kg = act + BTH + boff;
  const float* ifg = act + 2 * BTH + 2 * boff;
  const float* vog = act + 4 * BTH + 2 * boff;

  // stage k tile (64x128) and gate slices (64x64 each), coalesced
#pragma unroll
  for (int i = 0; i < 4; ++i) {
    const int u = tid + 512 * i;                 // f4 index, 2048 total
    const int r = u >> 5, c = (u & 31) * 4;
    *(float4*)&kt[r][c] = *(const float4*)(kg + (size_t)(t0 + r) * HH + c);
  }
#pragma unroll
  for (int i = 0; i < 2; ++i) {
    const int u = tid + 512 * i;                 // f4 index, 1024 total
    const int r = u >> 4, c = (u & 15) * 4;
    *(float4*)&ift[r][c] =
        *(const float4*)(ifg + (size_t)(t0 + r) * 2 * HH + 2 * p0 + c);
    *(float4*)&vot[r][c] =
        *(const float4*)(vog + (size_t)(t0 + r) * 2 * HH + 2 * p0 + c);
  }
  __syncthreads();

  const int pl = lane >> 4, cl = lane & 15;
  const int plocal = wid * 4 + pl;               // 0..31
  const int p = p0 + plocal;

  float C[8];
#pragma unroll
  for (int j = 0; j < 8; ++j) C[j] = 0.f;
  float Af = 1.f;

#pragma unroll 4
  for (int t = 0; t < CL; ++t) {
    const float2 gif = *(const float2*)&ift[t][2 * plocal];
    const float2 gvo = *(const float2*)&vot[t][2 * plocal];
    const float4 k0 = *(const float4*)&kt[t][cl * 4];
    const float4 k1 = *(const float4*)&kt[t][cl * 4 + 64];
    const float a = gif.x * gvo.x;               // i*v
    const float f = gif.y;
    C[0] = fmaf(f, C[0], a * k0.x);
    C[1] = fmaf(f, C[1], a * k0.y);
    C[2] = fmaf(f, C[2], a * k0.z);
    C[3] = fmaf(f, C[3], a * k0.w);
    C[4] = fmaf(f, C[4], a * k1.x);
    C[5] = fmaf(f, C[5], a * k1.y);
    C[6] = fmaf(f, C[6], a * k1.z);
    C[7] = fmaf(f, C[7], a * k1.w);
    Af *= f;
  }

  const size_t slot = (size_t)(b * 128 + p) * NCH + ch;
  *(float4*)(cbuf + slot * 128 + cl * 4) = make_float4(C[0], C[1], C[2], C[3]);
  *(float4*)(cbuf + slot * 128 + cl * 4 + 64) =
      make_float4(C[4], C[5], C[6], C[7]);
  if (cl == 0) abuf[slot] = Af;
}

// Compose the 8 chunk summaries per chain, in place (unchanged, proven).
__global__ __launch_bounds__(64)
void ccomb_kernel(float* __restrict__ cbuf, const float* __restrict__ abuf) {
  const int chain = blockIdx.x;        // b*128+p
  const int lane = threadIdx.x;
  const float av = abuf[(size_t)chain * 8 + (lane & 7)];
  float Cs0 = 0.f, Cs1 = 0.f;
#pragma unroll
  for (int g = 0; g < 8; ++g) {
    float* ptr = cbuf + ((size_t)chain * 8 + g) * 128 + 2 * lane;
    const float2 Bv = *(const float2*)ptr;
    const float Ag = rd_lane(av, g);
    *(float2*)ptr = make_float2(Cs0, Cs1);
    Cs0 = fmaf(Ag, Cs0, Bv.x);
    Cs1 = fmaf(Ag, Cs1, Bv.y);
  }
}

__global__ __launch_bounds__(512)
void hscan2_kernel(const float* __restrict__ act, float* __restrict__ hout,
                   const float* __restrict__ cbuf) {
  __shared__ __align__(16) float qt[CL][128];   // 32 KB
  __shared__ __align__(16) float kt[CL][128];   // 32 KB
  __shared__ __align__(16) float ift[CL][64];   // 16 KB
  __shared__ __align__(16) float vot[CL][64];   // 16 KB (o pre-scaled)
  const int tid = threadIdx.x;
  const int lane = tid & 63, wid = tid >> 6;
  const int blk = blockIdx.x;
  const int b = blk & 7, ch = (blk >> 3) & 7, qtr = blk >> 6;
  const int t0 = ch * CL;
  const int p0 = qtr * 32;
  const size_t boff = (size_t)b * TT * HH;
  const float* qg = act + boff;
  const float* kg = act + BTH + boff;
  const float* ifg = act + 2 * BTH + 2 * boff;
  const float* vog = act + 4 * BTH + 2 * boff;

#pragma unroll
  for (int i = 0; i < 4; ++i) {
    const int u = tid + 512 * i;
    const int r = u >> 5, c = (u & 31) * 4;
    *(float4*)&qt[r][c] = *(const float4*)(qg + (size_t)(t0 + r) * HH + c);
    *(float4*)&kt[r][c] = *(const float4*)(kg + (size_t)(t0 + r) * HH + c);
  }
#pragma unroll
  for (int i = 0; i < 2; ++i) {
    const int u = tid + 512 * i;
    const int r = u >> 4, c = (u & 15) * 4;
    *(float4*)&ift[r][c] =
        *(const float4*)(ifg + (size_t)(t0 + r) * 2 * HH + 2 * p0 + c);
    *(float4*)&vot[r][c] =
        *(const float4*)(vog + (size_t)(t0 + r) * 2 * HH + 2 * p0 + c);
  }
  __syncthreads();

  const int pl = lane >> 4, cl = lane & 15;
  const int plocal = wid * 4 + pl;
  const int p = p0 + plocal;

  // start-C for this chunk (exact, from ccomb)
  float C[8];
  {
    const size_t slot = (size_t)(b * 128 + p) * NCH + ch;
    const float4 c0 = *(const float4*)(cbuf + slot * 128 + cl * 4);
    const float4 c1 = *(const float4*)(cbuf + slot * 128 + cl * 4 + 64);
    C[0] = c0.x; C[1] = c0.y; C[2] = c0.z; C[3] = c0.w;
    C[4] = c1.x; C[5] = c1.y; C[6] = c1.z; C[7] = c1.w;
  }
  float* hbase = hout + boff + p;

#pragma unroll 4
  for (int t = 0; t < CL; ++t) {
    const float2 gif = *(const float2*)&ift[t][2 * plocal];
    const float2 gvo = *(const float2*)&vot[t][2 * plocal];
    const float4 q0 = *(const float4*)&qt[t][cl * 4];
    const float4 q1 = *(const float4*)&qt[t][cl * 4 + 64];
    const float4 k0 = *(const float4*)&kt[t][cl * 4];
    const float4 k1 = *(const float4*)&kt[t][cl * 4 + 64];
    // h-tilde partial from OLD C
    float s0 = C[0] * q0.x;
    float s1 = C[4] * q1.x;
    s0 = fmaf(C[1], q0.y, s0);
    s1 = fmaf(C[5], q1.y, s1);
    s0 = fmaf(C[2], q0.z, s0);
    s1 = fmaf(C[6], q1.z, s1);
    s0 = fmaf(C[3], q0.w, s0);
    s1 = fmaf(C[7], q1.w, s1);
    float s = s0 + s1;
    // C update
    const float a = gif.x * gvo.x;               // i*v
    const float f = gif.y;
    C[0] = fmaf(f, C[0], a * k0.x);
    C[1] = fmaf(f, C[1], a * k0.y);
    C[2] = fmaf(f, C[2], a * k0.z);
    C[3] = fmaf(f, C[3], a * k0.w);
    C[4] = fmaf(f, C[4], a * k1.x);
    C[5] = fmaf(f, C[5], a * k1.y);
    C[6] = fmaf(f, C[6], a * k1.z);
    C[7] = fmaf(f, C[7], a * k1.w);
    // reduce over the 16-lane row: lane cl==15 holds the full col-sum
    s = dpp_add<0x111>(s);
    s = dpp_add<0x112>(s);
    s = dpp_add<0x114>(s);
    s = dpp_add<0x118>(s);
    if (cl == 15) hbase[(size_t)(t0 + t) * HH] = s * gvo.y;  // o' = o*invden
  }
}

// ---------------------------------------------------------------------------
extern "C" void kernel_launch(void* const* d_in, const int* in_sizes, int n_in,
                              void* d_out, int out_size, void* d_ws,
                              size_t ws_size, hipStream_t stream) {
  (void)in_sizes; (void)n_in; (void)out_size; (void)ws_size;
  const float* x = (const float*)d_in[0];
  float* act = (float*)d_ws;            // 6 * BTH floats
  float* hbuf = act + 6 * BTH;          // BTH floats (layer-1 h)
  float* cbuf = act + 7 * BTH;          // 1024*8*128 floats
  float* abuf = cbuf + (size_t)1024 * 8 * 128;  // 8192 floats
  float* Wt = (float*)d_out;            // [0, 196608)
  float* segAB = Wt + 196608;           // [196608, 327680)
  float* nstart = Wt + 327680;          // [327680, 393216)

  WArgs wa;
  for (int j = 0; j < 6; ++j) wa.W[j] = (const float*)d_in[1 + j];
  transpose_w<<<dim3(16, 12), 256, 0, stream>>>(wa, Wt);

  for (int l = 0; l < 2; ++l) {
    BArgs ba;
    for (int j = 0; j < 6; ++j)
      ba.b[j] = (const float*)d_in[7 + j] + (size_t)l * HH;
    const float* wtl = Wt + (size_t)l * 6 * HH * DD;
    const float* xin = (l == 0) ? x : hbuf;
    float* hdst = (l == 0) ? hbuf : (float*)d_out;
    proj_kernel<<<dim3(BT_ / 32, 6), 256, 0, stream>>>(xin, wtl, ba, act);
    // n/denominator path (independent of C)
    nseg_kernel<<<512, 128, 0, stream>>>(act, segAB);
    nsum_kernel<<<1024, 64, 0, stream>>>(segAB, nstart);
    nexp_denom_kernel<<<512, 128, 0, stream>>>(act, nstart);
    // chunked C-scan, block-tiled: summaries -> start-C -> replay with h
    cseg2_kernel<<<256, 512, 0, stream>>>(act, cbuf, abuf);
    ccomb_kernel<<<1024, 64, 0, stream>>>(cbuf, abuf);
    hscan2_kernel<<<256, 512, 0, stream>>>(act, hdst, cbuf);
  }
}

// Round 7
// 216.692 us; speedup vs baseline: 1.3911x; 1.0175x over previous
//
#include <hip/hip_runtime.h>
#include <math.h>

// (B, T, D, H, L) = (8, 512, 128, 128, 2). All fp32 I/O.
#define BB 8
#define TT 512
#define DD 128
#define HH 128
#define BT_ (BB * TT)                 // 4096
#define CL 32                         // C-scan chunk length
#define NCH 16                        // number of chunks (TT/CL)
static const size_t BTH = (size_t)BT_ * HH;  // 524288

// ws layout: act planes [0,6*BTH) : q | k | ifpack(2*BTH) | vopack(2*BTH)
//   q:      act + 0      [row][h]
//   k:      act + BTH    [row][h]     (pre-scaled by 1/sqrt(H) in proj)
//   ifpack: act + 2*BTH  [row][2h+{0:i,1:f}]
//   vopack: act + 4*BTH  [row][2h+{0:v,1:o}]  (o *= invden in ndenom)
// hbuf = act + 6*BTH (layer-1 output).
// cbuf = act + 7*BTH: raw C-chunk summaries (1024 chains x 16 x 128 = 8 MB)
// abuf = cbuf + 1024*NCH*128: per-chunk A = prod f   (16K floats)
// nbufB = abuf + 1024*NCH:    per-chunk n-summary B  (16K floats)
// (ws_size = 256 MiB per the harness fill; ~23 MB used.)
// d_out: Wt [0,196608) transposed weights; consumed by both proj dispatches,
// then overwritten by the final hscan2 output (stream-ordered, safe).

struct WArgs { const float* W[6]; };
struct BArgs { const float* b[6]; };

template <int CTRL>
__device__ __forceinline__ float dpp_add(float x) {
  int y = __builtin_amdgcn_update_dpp(0, __builtin_bit_cast(int, x), CTRL,
                                      0xF, 0xF, true);
  return x + __builtin_bit_cast(float, y);
}

// ---------------------------------------------------------------------------
// Transpose all 12 weight slabs: Wt[l*6+p][d][h] = W_p[l][h][d].
// ---------------------------------------------------------------------------
__global__ __launch_bounds__(256)
void transpose_w(WArgs w, float* __restrict__ Wt) {
  __shared__ float t[32][33];
  const int l = blockIdx.y / 6, p = blockIdx.y % 6;
  const float* src = w.W[p] + (size_t)l * HH * DD;
  float* dst = Wt + (size_t)blockIdx.y * HH * DD;
  const int ty0 = (blockIdx.x >> 2) * 32, tx0 = (blockIdx.x & 3) * 32;
  const int tx = threadIdx.x & 31, ty = threadIdx.x >> 5;
#pragma unroll
  for (int j = 0; j < 32; j += 8)
    t[ty + j][tx] = src[(size_t)(ty0 + ty + j) * DD + tx0 + tx];
  __syncthreads();
#pragma unroll
  for (int j = 0; j < 32; j += 8)
    dst[(size_t)(tx0 + ty + j) * HH + ty0 + tx] = t[tx][ty + j];
}

// ---------------------------------------------------------------------------
// Projection: out[p][row][h] = act_p( sum_d X[row][d] * Wt_p[d][h] + b_p[h] )
// grid (BT_/32, 6), block 256. Thread = 2 rows x 8 h. (proven)
// ---------------------------------------------------------------------------
__global__ __launch_bounds__(256)
void proj_kernel(const float* __restrict__ X, const float* __restrict__ Wtl,
                 BArgs args, float* __restrict__ act) {
  __shared__ float xs[32][132];
  const int p = blockIdx.y;
  const int row0 = blockIdx.x * 32;
  const int tid = threadIdx.x;
  {
    const float4* xg = (const float4*)(X + (size_t)row0 * DD);
#pragma unroll
    for (int i = 0; i < 4; ++i) {
      int u = tid + 256 * i;
      float4 v = xg[u];
      *(float4*)&xs[u >> 5][(u & 31) * 4] = v;
    }
  }
  __syncthreads();

  const int h0 = (tid & 15) * 8;
  const int r0 = (tid >> 4) * 2;
  const float* wtp = Wtl + (size_t)p * HH * DD;

  float acc[2][8];
#pragma unroll
  for (int r = 0; r < 2; ++r)
#pragma unroll
    for (int j = 0; j < 8; ++j) acc[r][j] = 0.f;

  for (int d0 = 0; d0 < DD; d0 += 4) {
    float4 wa[4], wb[4];
#pragma unroll
    for (int i = 0; i < 4; ++i) {
      wa[i] = *(const float4*)(wtp + (size_t)(d0 + i) * HH + h0);
      wb[i] = *(const float4*)(wtp + (size_t)(d0 + i) * HH + h0 + 4);
    }
    float4 x0 = *(const float4*)&xs[r0][d0];
    float4 x1 = *(const float4*)&xs[r0 + 1][d0];
    const float xa[4] = {x0.x, x0.y, x0.z, x0.w};
    const float xb[4] = {x1.x, x1.y, x1.z, x1.w};
#pragma unroll
    for (int i = 0; i < 4; ++i) {
      acc[0][0] = fmaf(xa[i], wa[i].x, acc[0][0]);
      acc[0][1] = fmaf(xa[i], wa[i].y, acc[0][1]);
      acc[0][2] = fmaf(xa[i], wa[i].z, acc[0][2]);
      acc[0][3] = fmaf(xa[i], wa[i].w, acc[0][3]);
      acc[0][4] = fmaf(xa[i], wb[i].x, acc[0][4]);
      acc[0][5] = fmaf(xa[i], wb[i].y, acc[0][5]);
      acc[0][6] = fmaf(xa[i], wb[i].z, acc[0][6]);
      acc[0][7] = fmaf(xa[i], wb[i].w, acc[0][7]);
      acc[1][0] = fmaf(xb[i], wa[i].x, acc[1][0]);
      acc[1][1] = fmaf(xb[i], wa[i].y, acc[1][1]);
      acc[1][2] = fmaf(xb[i], wa[i].z, acc[1][2]);
      acc[1][3] = fmaf(xb[i], wa[i].w, acc[1][3]);
      acc[1][4] = fmaf(xb[i], wb[i].x, acc[1][4]);
      acc[1][5] = fmaf(xb[i], wb[i].y, acc[1][5]);
      acc[1][6] = fmaf(xb[i], wb[i].z, acc[1][6]);
      acc[1][7] = fmaf(xb[i], wb[i].w, acc[1][7]);
    }
  }

  const float4 b0 = *(const float4*)(args.b[p] + h0);
  const float4 b1 = *(const float4*)(args.b[p] + h0 + 4);
  const float bias[8] = {b0.x, b0.y, b0.z, b0.w, b1.x, b1.y, b1.z, b1.w};
#pragma unroll
  for (int r = 0; r < 2; ++r) {
    const size_t row = (size_t)row0 + r0 + r;
    float v[8];
#pragma unroll
    for (int j = 0; j < 8; ++j) {
      float a = acc[r][j] + bias[j];
      if (p == 1)      a *= 0.088388347648318447f;   // 1/sqrt(128)
      else if (p == 3) a = __expf(a);
      else if (p >= 4) a = 1.0f / (1.0f + __expf(-a));
      v[j] = a;
    }
    if (p == 0) {
      float* dst = act + row * HH + h0;
      *(float4*)dst = make_float4(v[0], v[1], v[2], v[3]);
      *(float4*)(dst + 4) = make_float4(v[4], v[5], v[6], v[7]);
    } else if (p == 1) {
      float* dst = act + BTH + row * HH + h0;
      *(float4*)dst = make_float4(v[0], v[1], v[2], v[3]);
      *(float4*)(dst + 4) = make_float4(v[4], v[5], v[6], v[7]);
    } else if (p == 3 || p == 4) {       // i -> slot 0, f -> slot 1
      float* dst = act + 2 * BTH + row * 2 * HH + 2 * h0 + (p == 3 ? 0 : 1);
#pragma unroll
      for (int j = 0; j < 8; ++j) dst[2 * j] = v[j];
    } else {                             // v -> slot 0, o -> slot 1
      float* dst = act + 4 * BTH + row * 2 * HH + 2 * h0 + (p == 2 ? 0 : 1);
#pragma unroll
      for (int j = 0; j < 8; ++j) dst[2 * j] = v[j];
    }
  }
}

// ---------------------------------------------------------------------------
// cseg2 (+fused n-summary): block-tiled chunk summaries. One 512-thread
// block per (b, chunk, p-quarter): grid 512 (2 blocks/CU). Block stages its
// k tile + 32-p gate slices into LDS once. Lane (pl=lane>>4, cl=lane&15)
// owns p-row = qtr*32 + wid*4 + pl, cols cl*4+{0..3}+{0,64}.
// Per t also advances the n-summary Bn = f*Bn + i*k[p] (LDS broadcast read);
// A = prod f is shared by C- and n-scans (same scalar).
// ---------------------------------------------------------------------------
__global__ __launch_bounds__(512)
void cseg2_kernel(const float* __restrict__ act, float* __restrict__ cbuf,
                  float* __restrict__ abuf, float* __restrict__ nbufB) {
  __shared__ __align__(16) float kt[CL][128];
  __shared__ __align__(16) float ift[CL][64];
  __shared__ __align__(16) float vot[CL][64];
  const int tid = threadIdx.x;
  const int lane = tid & 63, wid = tid >> 6;
  const int blk = blockIdx.x;
  const int b = blk & 7, ch = (blk >> 3) & (NCH - 1), qtr = blk >> 7;
  const int t0 = ch * CL;
  const int p0 = qtr * 32;
  const size_t boff = (size_t)b * TT * HH;
  const float* kg = act + BTH + boff;
  const float* ifg = act + 2 * BTH + 2 * boff;
  const float* vog = act + 4 * BTH + 2 * boff;

#pragma unroll
  for (int i = 0; i < CL / 16; ++i) {
    const int u = tid + 512 * i;                 // f4 index
    const int r = u >> 5, c = (u & 31) * 4;
    *(float4*)&kt[r][c] = *(const float4*)(kg + (size_t)(t0 + r) * HH + c);
  }
  {
    const int r = tid >> 4, c = (tid & 15) * 4;  // 512 f4 = CL x 64
    *(float4*)&ift[r][c] =
        *(const float4*)(ifg + (size_t)(t0 + r) * 2 * HH + 2 * p0 + c);
    *(float4*)&vot[r][c] =
        *(const float4*)(vog + (size_t)(t0 + r) * 2 * HH + 2 * p0 + c);
  }
  __syncthreads();

  const int pl = lane >> 4, cl = lane & 15;
  const int plocal = wid * 4 + pl;               // 0..31
  const int p = p0 + plocal;

  float C[8];
#pragma unroll
  for (int j = 0; j < 8; ++j) C[j] = 0.f;
  float Af = 1.f, Bn = 0.f;

#pragma unroll 4
  for (int t = 0; t < CL; ++t) {
    const float2 gif = *(const float2*)&ift[t][2 * plocal];
    const float2 gvo = *(const float2*)&vot[t][2 * plocal];
    const float4 k0 = *(const float4*)&kt[t][cl * 4];
    const float4 k1 = *(const float4*)&kt[t][cl * 4 + 64];
    const float kp = kt[t][p];                   // broadcast across cl lanes
    const float a = gif.x * gvo.x;               // i*v
    const float f = gif.y;
    C[0] = fmaf(f, C[0], a * k0.x);
    C[1] = fmaf(f, C[1], a * k0.y);
    C[2] = fmaf(f, C[2], a * k0.z);
    C[3] = fmaf(f, C[3], a * k0.w);
    C[4] = fmaf(f, C[4], a * k1.x);
    C[5] = fmaf(f, C[5], a * k1.y);
    C[6] = fmaf(f, C[6], a * k1.z);
    C[7] = fmaf(f, C[7], a * k1.w);
    Af *= f;
    Bn = fmaf(f, Bn, gif.x * kp);                // n-summary
  }

  const size_t slot = (size_t)(b * 128 + p) * NCH + ch;
  *(float4*)(cbuf + slot * 128 + cl * 4) = make_float4(C[0], C[1], C[2], C[3]);
  *(float4*)(cbuf + slot * 128 + cl * 4 + 64) =
      make_float4(C[4], C[5], C[6], C[7]);
  if (cl == 0) {
    abuf[slot] = Af;
    nbufB[slot] = Bn;
  }
}

// ---------------------------------------------------------------------------
// ndenom: per (b, chunk) block of 128 threads (p). Inline prefix-compose of
// the <=15 prior n-chunk summaries, then replay the 32 steps in 8-t groups
// with the proven LDS-transpose denominator reduce; scale o in place.
// grid 128 (b = blk&7, ch = blk>>3).
// ---------------------------------------------------------------------------
__global__ __launch_bounds__(128)
void ndenom_kernel(float* __restrict__ act, const float* __restrict__ abuf,
                   const float* __restrict__ nbufB) {
  __shared__ float plds[8][132];
  __shared__ float den[8];
  const int b = blockIdx.x & 7, ch = blockIdx.x >> 3;
  const int p = threadIdx.x;
  const size_t boff = (size_t)b * TT * HH;
  const float* qp = act + boff + p;
  const float* kp = act + BTH + boff + p;
  const float* ifp = act + 2 * BTH + 2 * boff + 2 * p;
  float* vop = act + 4 * BTH + 2 * boff;
  const size_t cb = (size_t)(b * 128 + p) * NCH;

  float n = 0.f;                        // n at chunk start
#pragma unroll 1
  for (int g = 0; g < ch; ++g) n = fmaf(abuf[cb + g], n, nbufB[cb + g]);

#pragma unroll 1
  for (int grp = 0; grp < CL / 8; ++grp) {
    const int t0 = ch * CL + grp * 8;
    float prod[8];
#pragma unroll
    for (int j = 0; j < 8; ++j) {
      const float2 iff = *(const float2*)(ifp + (size_t)(t0 + j) * 2 * HH);
      const float kv = kp[(size_t)(t0 + j) * HH];
      const float qv = qp[(size_t)(t0 + j) * HH];
      prod[j] = n * qv;                 // OLD n (n_{t-1})
      n = fmaf(iff.y, n, iff.x * kv);
    }
#pragma unroll
    for (int j = 0; j < 8; ++j) plds[j][p] = prod[j];
    __syncthreads();
    {
      const int j = p >> 4, c = p & 15; // 16 threads per t
      const float4 a = *(const float4*)&plds[j][c * 8];
      const float4 d = *(const float4*)&plds[j][c * 8 + 4];
      float s = ((a.x + a.y) + (a.z + a.w)) + ((d.x + d.y) + (d.z + d.w));
      s = dpp_add<0x111>(s);
      s = dpp_add<0x112>(s);
      s = dpp_add<0x114>(s);
      s = dpp_add<0x118>(s);            // lane 15 of each 16-row = full sum
      if ((p & 15) == 15)
        den[j] = __builtin_amdgcn_rcpf(fmaxf(fabsf(s), 1.0f));
    }
    __syncthreads();
#pragma unroll
    for (int j = 0; j < 8; ++j)
      vop[(size_t)(t0 + j) * 2 * HH + 2 * p + 1] *= den[j];
  }
}

// ---------------------------------------------------------------------------
// hscan2: replay chunk from inline-composed start-C with h output (proven
// block-tiled structure). grid 512 (b, ch, qtr), block 512.
// ---------------------------------------------------------------------------
__global__ __launch_bounds__(512)
void hscan2_kernel(const float* __restrict__ act, float* __restrict__ hout,
                   const float* __restrict__ cbuf,
                   const float* __restrict__ abuf) {
  __shared__ __align__(16) float qt[CL][128];
  __shared__ __align__(16) float kt[CL][128];
  __shared__ __align__(16) float ift[CL][64];
  __shared__ __align__(16) float vot[CL][64];  // o pre-scaled by invden
  const int tid = threadIdx.x;
  const int lane = tid & 63, wid = tid >> 6;
  const int blk = blockIdx.x;
  const int b = blk & 7, ch = (blk >> 3) & (NCH - 1), qtr = blk >> 7;
  const int t0 = ch * CL;
  const int p0 = qtr * 32;
  const size_t boff = (size_t)b * TT * HH;
  const float* qg = act + boff;
  const float* kg = act + BTH + boff;
  const float* ifg = act + 2 * BTH + 2 * boff;
  const float* vog = act + 4 * BTH + 2 * boff;

#pragma unroll
  for (int i = 0; i < CL / 16; ++i) {
    const int u = tid + 512 * i;
    const int r = u >> 5, c = (u & 31) * 4;
    *(float4*)&qt[r][c] = *(const float4*)(qg + (size_t)(t0 + r) * HH + c);
    *(float4*)&kt[r][c] = *(const float4*)(kg + (size_t)(t0 + r) * HH + c);
  }
  {
    const int r = tid >> 4, c = (tid & 15) * 4;
    *(float4*)&ift[r][c] =
        *(const float4*)(ifg + (size_t)(t0 + r) * 2 * HH + 2 * p0 + c);
    *(float4*)&vot[r][c] =
        *(const float4*)(vog + (size_t)(t0 + r) * 2 * HH + 2 * p0 + c);
  }
  __syncthreads();

  const int pl = lane >> 4, cl = lane & 15;
  const int plocal = wid * 4 + pl;
  const int p = p0 + plocal;

  // start-C: inline compose of prior chunk summaries (Cs = A_g*Cs + B_g)
  float C[8];
#pragma unroll
  for (int j = 0; j < 8; ++j) C[j] = 0.f;
  {
    const size_t cb = (size_t)(b * 128 + p) * NCH;
#pragma unroll 1
    for (int g = 0; g < ch; ++g) {
      const float a = abuf[cb + g];
      const float4 b0 = *(const float4*)(cbuf + (cb + g) * 128 + cl * 4);
      const float4 b1 = *(const float4*)(cbuf + (cb + g) * 128 + cl * 4 + 64);
      C[0] = fmaf(a, C[0], b0.x);
      C[1] = fmaf(a, C[1], b0.y);
      C[2] = fmaf(a, C[2], b0.z);
      C[3] = fmaf(a, C[3], b0.w);
      C[4] = fmaf(a, C[4], b1.x);
      C[5] = fmaf(a, C[5], b1.y);
      C[6] = fmaf(a, C[6], b1.z);
      C[7] = fmaf(a, C[7], b1.w);
    }
  }
  float* hbase = hout + boff + p;

#pragma unroll 4
  for (int t = 0; t < CL; ++t) {
    const float2 gif = *(const float2*)&ift[t][2 * plocal];
    const float2 gvo = *(const float2*)&vot[t][2 * plocal];
    const float4 q0 = *(const float4*)&qt[t][cl * 4];
    const float4 q1 = *(const float4*)&qt[t][cl * 4 + 64];
    const float4 k0 = *(const float4*)&kt[t][cl * 4];
    const float4 k1 = *(const float4*)&kt[t][cl * 4 + 64];
    // h-tilde partial from OLD C
    float s0 = C[0] * q0.x;
    float s1 = C[4] * q1.x;
    s0 = fmaf(C[1], q0.y, s0);
    s1 = fmaf(C[5], q1.y, s1);
    s0 = fmaf(C[2], q0.z, s0);
    s1 = fmaf(C[6], q1.z, s1);
    s0 = fmaf(C[3], q0.w, s0);
    s1 = fmaf(C[7], q1.w, s1);
    float s = s0 + s1;
    // C update
    const float a = gif.x * gvo.x;               // i*v
    const float f = gif.y;
    C[0] = fmaf(f, C[0], a * k0.x);
    C[1] = fmaf(f, C[1], a * k0.y);
    C[2] = fmaf(f, C[2], a * k0.z);
    C[3] = fmaf(f, C[3], a * k0.w);
    C[4] = fmaf(f, C[4], a * k1.x);
    C[5] = fmaf(f, C[5], a * k1.y);
    C[6] = fmaf(f, C[6], a * k1.z);
    C[7] = fmaf(f, C[7], a * k1.w);
    // reduce over the 16-lane row: lane cl==15 holds the full col-sum
    s = dpp_add<0x111>(s);
    s = dpp_add<0x112>(s);
    s = dpp_add<0x114>(s);
    s = dpp_add<0x118>(s);
    if (cl == 15) hbase[(size_t)(t0 + t) * HH] = s * gvo.y;  // o' = o*invden
  }
}

// ---------------------------------------------------------------------------
extern "C" void kernel_launch(void* const* d_in, const int* in_sizes, int n_in,
                              void* d_out, int out_size, void* d_ws,
                              size_t ws_size, hipStream_t stream) {
  (void)in_sizes; (void)n_in; (void)out_size; (void)ws_size;
  const float* x = (const float*)d_in[0];
  float* act = (float*)d_ws;                     // 6 * BTH floats
  float* hbuf = act + 6 * BTH;                   // BTH floats (layer-1 h)
  float* cbuf = act + 7 * BTH;                   // 1024*NCH*128 floats (8 MB)
  float* abuf = cbuf + (size_t)1024 * NCH * 128; // 16K floats
  float* nbufB = abuf + (size_t)1024 * NCH;      // 16K floats
  float* Wt = (float*)d_out;                     // [0, 196608)

  WArgs wa;
  for (int j = 0; j < 6; ++j) wa.W[j] = (const float*)d_in[1 + j];
  transpose_w<<<dim3(16, 12), 256, 0, stream>>>(wa, Wt);

  for (int l = 0; l < 2; ++l) {
    BArgs ba;
    for (int j = 0; j < 6; ++j)
      ba.b[j] = (const float*)d_in[7 + j] + (size_t)l * HH;
    const float* wtl = Wt + (size_t)l * 6 * HH * DD;
    const float* xin = (l == 0) ? x : hbuf;
    float* hdst = (l == 0) ? hbuf : (float*)d_out;
    proj_kernel<<<dim3(BT_ / 32, 6), 256, 0, stream>>>(xin, wtl, ba, act);
    cseg2_kernel<<<512, 512, 0, stream>>>(act, cbuf, abuf, nbufB);
    ndenom_kernel<<<128, 128, 0, stream>>>(act, abuf, nbufB);
    hscan2_kernel<<<512, 512, 0, stream>>>(act, hdst, cbuf, abuf);
  }
}